// Round 5
// baseline (378.417 us; speedup 1.0000x reference)
//
#include <hip/hip_runtime.h>
#include <stdint.h>
#include <cmath>

// 4096x4096x3 f32 -> gray -> 3x3 gaussian (reflect) -> exact 98.7% quantile
// threshold -> mask -> 5x5 binary opening -> int32.
//
// Quantile: pos = fl(fl(0.987)*16777215.0f) = 16559111.0 exactly => threshold
// is order statistic #16559111. 2-level radix select on u = floor(blur*2^28);
// mask = (u >= ustar). absmax=0 validated rounds 1-4.

#define HH 4096
#define WW 4096
#define KRANK 16559111u
#define CAP 65536u
#define NBLK 512          // blur blocks (= hist partials)

__device__ __forceinline__ unsigned ukey(float v) {
  return (unsigned)(v * 268435456.0f);
}
__device__ __forceinline__ int refl(int i) {
  return i < 0 ? -i : (i > 4095 ? 8190 - i : i);
}
__device__ __forceinline__ float grayf(float r, float g, float b) {
  return __fadd_rn(__fadd_rn(__fmul_rn(0.2989f, r), __fmul_rn(0.587f, g)),
                   __fmul_rn(0.114f, b));
}
__device__ __forceinline__ float tap3(float a, float b, float c, float kn0, float kn1) {
  return __fadd_rn(__fadd_rn(__fmul_rn(kn0, a), __fmul_rn(kn1, b)),
                   __fmul_rn(kn0, c));
}

struct Raw { float4 R, G, B; float hr, hg, hb; };

// ---------------- K1: gray + separable blur + per-block hist partials ------
// Block = 512 thr = 8 waves; wave owns 256 cols x 16 rows (lane = 4 cols).
// Grid = 16 col-tiles x 32 row-strips (128 rows/block) = 512 blocks.
__global__ __launch_bounds__(512, 4) void k_blur(const float* __restrict__ img,
    float4* __restrict__ blur4, unsigned* __restrict__ hist_part,
    float kn0, float kn1) {
  __shared__ unsigned hist[4096];
  const int tid = threadIdx.x;
  #pragma unroll
  for (int i = tid; i < 4096; i += 512) hist[i] = 0u;
  __syncthreads();

  const int lane = tid & 63, wv = tid >> 6;
  const int bc = (blockIdx.x & 15) << 8;        // column base
  const int r0 = (blockIdx.x >> 4) << 7;        // row base (128 rows/block)
  const int rs = r0 + (wv << 4);                // wave's first output row
  const float* __restrict__ Rp = img;
  const float* __restrict__ Gp = img + 16777216;
  const float* __restrict__ Bp = img + 33554432;
  const int c4 = bc + (lane << 2);
  const int colL = (bc == 0) ? 1 : bc - 1;            // reflect(-1)=1
  const int colR = (bc == 3840) ? 4094 : bc + 256;    // reflect(4096)=4094
  const int hc = (lane == 0) ? colL : ((lane == 63) ? colR : c4);

  auto ld = [&](int r) -> Raw {
    Raw a;
    const size_t base = ((size_t)refl(r) << 12);
    a.R = *(const float4*)(Rp + base + c4);
    a.G = *(const float4*)(Gp + base + c4);
    a.B = *(const float4*)(Bp + base + c4);
    a.hr = Rp[base + hc]; a.hg = Gp[base + hc]; a.hb = Bp[base + hc];
    return a;
  };
  auto hcomp = [&](const Raw& a) -> float4 {
    float4 g;
    g.x = grayf(a.R.x, a.G.x, a.B.x);
    g.y = grayf(a.R.y, a.G.y, a.B.y);
    g.z = grayf(a.R.z, a.G.z, a.B.z);
    g.w = grayf(a.R.w, a.G.w, a.B.w);
    float ghalo = grayf(a.hr, a.hg, a.hb);
    float gl = __shfl_up(g.w, 1);
    float gr_ = __shfl_down(g.x, 1);
    gl = (lane == 0) ? ghalo : gl;
    gr_ = (lane == 63) ? ghalo : gr_;
    float4 h;
    h.x = tap3(gl, g.x, g.y, kn0, kn1);
    h.y = tap3(g.x, g.y, g.z, kn0, kn1);
    h.z = tap3(g.y, g.z, g.w, kn0, kn1);
    h.w = tap3(g.z, g.w, gr_, kn0, kn1);
    return h;
  };

  Raw A = ld(rs - 1);
  Raw B = ld(rs);
  float4 h0 = hcomp(A);
  Raw C = ld(rs + 1);
  float4 h1 = hcomp(B);
  Raw D;
  #pragma unroll
  for (int i = 0; i < 16; ++i) {
    if (i < 15) D = ld(rs + 2 + i);     // prefetch one row ahead
    float4 h2 = hcomp(C);
    float4 v;
    v.x = tap3(h0.x, h1.x, h2.x, kn0, kn1);
    v.y = tap3(h0.y, h1.y, h2.y, kn0, kn1);
    v.z = tap3(h0.z, h1.z, h2.z, kn0, kn1);
    v.w = tap3(h0.w, h1.w, h2.w, kn0, kn1);
    blur4[(((size_t)(rs + i) << 12) + c4) >> 2] = v;
    atomicAdd(&hist[ukey(v.x) >> 16], 1u);
    atomicAdd(&hist[ukey(v.y) >> 16], 1u);
    atomicAdd(&hist[ukey(v.z) >> 16], 1u);
    atomicAdd(&hist[ukey(v.w) >> 16], 1u);
    h0 = h1; h1 = h2; C = D;
  }
  __syncthreads();
  // deterministic flush: no atomics, coalesced dword stores
  unsigned* dst = hist_part + (size_t)blockIdx.x * 4096;
  #pragma unroll
  for (int i = tid; i < 4096; i += 512) dst[i] = hist[i];
}

// ---------------- K1b: reduce 512 partial hists -> hist1 -------------------
__global__ __launch_bounds__(64) void k_hred(const unsigned* __restrict__ hp,
                                             unsigned* __restrict__ hist1) {
  const int t = blockIdx.x * 64 + threadIdx.x;   // bin id, grid 64x64 = 4096
  unsigned s = 0;
  #pragma unroll 8
  for (int k = 0; k < NBLK; ++k) s += hp[k * 4096 + t];
  hist1[t] = s;
}

// ---------------- K2: select level-1 bin containing rank KRANK -------------
__global__ __launch_bounds__(256) void k_sel1(const unsigned* __restrict__ hist1,
                                              unsigned* __restrict__ sel) {
  __shared__ unsigned part[256];
  const int t = threadIdx.x;
  unsigned loc[16];
  unsigned s = 0;
  for (int i = 0; i < 16; ++i) { loc[i] = hist1[t * 16 + i]; s += loc[i]; }
  part[t] = s;
  __syncthreads();
  for (int off = 1; off < 256; off <<= 1) {
    unsigned v = (t >= off) ? part[t - off] : 0u;
    __syncthreads();
    part[t] += v;
    __syncthreads();
  }
  unsigned incl = part[t], excl = incl - s;
  if (excl <= KRANK && KRANK < incl) {
    unsigned p = excl;
    for (int i = 0; i < 16; ++i) {
      if (KRANK < p + loc[i]) { sel[0] = (unsigned)(t * 16 + i); sel[1] = KRANK - p; break; }
      p += loc[i];
    }
  }
}

// ---------------- K3: fused mask bits + hist2 + block-aggregated list ------
// Grid 2048 blocks x 256 thr; block handles 8192 consecutive pixels (2 rows).
__global__ __launch_bounds__(256) void k_pass2(const float* __restrict__ blur,
    const unsigned* __restrict__ sel, unsigned* __restrict__ hist2,
    unsigned* __restrict__ cnt, unsigned long long* __restrict__ list,
    unsigned long long* __restrict__ mbits) {
  __shared__ unsigned lcnt, lbase;
  __shared__ unsigned lidx[256];
  __shared__ unsigned short lkey[256];
  if (threadIdx.x == 0) lcnt = 0u;
  __syncthreads();
  const unsigned b1 = sel[0];
  const unsigned ub = (b1 + 1u) << 16;
  const unsigned base = blockIdx.x * 8192u + threadIdx.x;
  #pragma unroll 4
  for (int it = 0; it < 32; ++it) {
    unsigned i = base + (unsigned)it * 256u;
    unsigned u = ukey(blur[i]);
    unsigned long long w = __ballot(u >= ub);
    if ((threadIdx.x & 63) == 0) mbits[i >> 6] = w;
    if ((u >> 16) == b1) {
      atomicAdd(&hist2[u & 0xFFFFu], 1u);
      unsigned x = atomicAdd(&lcnt, 1u);
      if (x < 256u) { lidx[x] = i; lkey[x] = (unsigned short)(u & 0xFFFFu); }
      else {
        unsigned g = atomicAdd(cnt, 1u);
        if (g < CAP) list[g] = ((unsigned long long)i << 16) | (u & 0xFFFFu);
      }
    }
  }
  __syncthreads();
  unsigned n = lcnt > 256u ? 256u : lcnt;
  if (threadIdx.x == 0 && n) lbase = atomicAdd(cnt, n);
  __syncthreads();
  if (threadIdx.x < n) {
    unsigned g = lbase + threadIdx.x;
    if (g < CAP)
      list[g] = ((unsigned long long)lidx[threadIdx.x] << 16) | (unsigned)lkey[threadIdx.x];
  }
}

// ---------------- K4: select low16 of rank key + fixup in-bin mask bits ----
__global__ __launch_bounds__(1024) void k_sel2fix(const unsigned* __restrict__ hist2,
    const unsigned* __restrict__ sel, const unsigned* __restrict__ cnt,
    const unsigned long long* __restrict__ list,
    unsigned long long* __restrict__ mbits) {
  __shared__ unsigned part[1024];
  __shared__ unsigned sLo;
  const int t = threadIdx.x;
  unsigned loc[64];
  const uint4* h4 = (const uint4*)hist2;
  unsigned s = 0;
  #pragma unroll
  for (int j = 0; j < 16; ++j) {
    uint4 q = h4[t * 16 + j];
    loc[4 * j] = q.x; loc[4 * j + 1] = q.y; loc[4 * j + 2] = q.z; loc[4 * j + 3] = q.w;
    s += q.x + q.y + q.z + q.w;
  }
  part[t] = s;
  __syncthreads();
  for (int off = 1; off < 1024; off <<= 1) {
    unsigned v = (t >= off) ? part[t - off] : 0u;
    __syncthreads();
    part[t] += v;
    __syncthreads();
  }
  unsigned incl = part[t], excl = incl - s;
  const unsigned r1 = sel[1];
  if (excl <= r1 && r1 < incl) {
    unsigned p = excl;
    for (int i = 0; i < 64; ++i) {
      if (r1 < p + loc[i]) { sLo = (unsigned)t * 64u + i; break; }
      p += loc[i];
    }
  }
  __syncthreads();
  const unsigned lo = sLo;
  unsigned n = *cnt; if (n > CAP) n = CAP;
  for (unsigned j = t; j < n; j += 1024) {
    unsigned long long e = list[j];
    if ((unsigned)(e & 0xFFFFu) >= lo) {
      unsigned long long pix = e >> 16;
      atomicOr(&mbits[pix >> 6], 1ull << (pix & 63));
    }
  }
}

// ---------------- K5: fused 5x5 erode (zero border) + dilate + int32 out ---
__global__ __launch_bounds__(256) void k_morph(
    const unsigned long long* __restrict__ mbits, int4* __restrict__ out4) {
  __shared__ unsigned long long er[12][64];
  __shared__ unsigned long long dl[8][64];
  const int r0 = blockIdx.x << 3;
  for (int t = threadIdx.x; t < 12 * 64; t += 256) {
    int lr = t >> 6, wc = t & 63;
    int rr = r0 - 2 + lr;
    unsigned long long acc = 0ull;
    if (rr >= 0 && rr < HH) {
      acc = ~0ull;
      #pragma unroll
      for (int dr = -2; dr <= 2; ++dr) {
        int mr = rr + dr;
        unsigned long long h = 0ull;
        if (mr >= 0 && mr < HH) {
          int rb = (mr << 6) + wc;
          unsigned long long C = mbits[rb];
          unsigned long long L = (wc > 0) ? mbits[rb - 1] : 0ull;
          unsigned long long R = (wc < 63) ? mbits[rb + 1] : 0ull;
          h = C & ((C >> 1) | (R << 63)) & ((C >> 2) | (R << 62))
                & ((C << 1) | (L >> 63)) & ((C << 2) | (L >> 62));
        }
        acc &= h;
      }
    }
    er[lr][wc] = acc;
  }
  __syncthreads();
  for (int t = threadIdx.x; t < 8 * 64; t += 256) {
    int lr = t >> 6, wc = t & 63;
    unsigned long long acc = 0ull;
    #pragma unroll
    for (int dr = 0; dr <= 4; ++dr) {
      unsigned long long C = er[lr + dr][wc];
      unsigned long long L = (wc > 0) ? er[lr + dr][wc - 1] : 0ull;
      unsigned long long R = (wc < 63) ? er[lr + dr][wc + 1] : 0ull;
      acc |= C | ((C >> 1) | (R << 63)) | ((C >> 2) | (R << 62))
               | ((C << 1) | (L >> 63)) | ((C << 2) | (L >> 62));
    }
    dl[lr][wc] = acc;
  }
  __syncthreads();
  const size_t p0 = (size_t)r0 << 10;
  for (int j = threadIdx.x; j < 8192; j += 256) {
    unsigned long long word = dl[j >> 10][(j >> 4) & 63];
    unsigned nib = (unsigned)(word >> ((j & 15) << 2)) & 0xFu;
    out4[p0 + j] = make_int4(nib & 1, (nib >> 1) & 1, (nib >> 2) & 1, (nib >> 3) & 1);
  }
}

// ---------------------------------------------------------------------------
extern "C" void kernel_launch(void* const* d_in, const int* in_sizes, int n_in,
                              void* d_out, int out_size, void* d_ws, size_t ws_size,
                              hipStream_t stream) {
  (void)in_sizes; (void)n_in; (void)out_size; (void)ws_size;
  const float* img = (const float*)d_in[0];
  char* ws = (char*)d_ws;

  float* blur = (float*)ws;                                          // 64 MB
  unsigned long long* mbits = (unsigned long long*)(ws + 67108864);  // 2 MB
  unsigned* hist_part = (unsigned*)(ws + 69206016);                  // 8 MB
  unsigned* hist1 = (unsigned*)(ws + 77594624);                      // 16 KB
  unsigned* hist2 = (unsigned*)(ws + 77611008);                      // 256 KB
  unsigned* cnt   = (unsigned*)(ws + 77873152);                      // 64 B
  unsigned* sel   = (unsigned*)(ws + 77873216);                      // 64 B
  unsigned long long* list = (unsigned long long*)(ws + 77873280);   // 512 KB

  float t = 1.0f / 0.8f;
  float k0 = expf(-0.5f * (t * t));
  float k1 = 1.0f;
  float s = (k0 + k1) + k0;
  float kn0 = k0 / s, kn1 = k1 / s;

  hipMemsetAsync(hist2, 0, 262144 + 64, stream);   // hist2 + cnt
  k_blur<<<512, 512, 0, stream>>>(img, (float4*)blur, hist_part, kn0, kn1);
  k_hred<<<64, 64, 0, stream>>>(hist_part, hist1);
  k_sel1<<<1, 256, 0, stream>>>(hist1, sel);
  k_pass2<<<2048, 256, 0, stream>>>(blur, sel, hist2, cnt, list, mbits);
  k_sel2fix<<<1, 1024, 0, stream>>>(hist2, sel, cnt, list, mbits);
  k_morph<<<512, 256, 0, stream>>>(mbits, (int4*)d_out);
}

// Round 8
// 368.511 us; speedup vs baseline: 1.0269x; 1.0269x over previous
//
#include <hip/hip_runtime.h>
#include <stdint.h>
#include <cmath>

// 4096x4096x3 f32 -> gray -> 3x3 gaussian (reflect) -> exact 98.7% quantile
// threshold -> mask -> 5x5 binary opening -> int32.
//
// Quantile: pos = fl(fl(0.987)*16777215.0f) = 16559111.0 exactly => threshold
// is order statistic #16559111. 2-level radix select on u = floor(blur*2^28);
// mask = (u >= ustar). absmax=0 validated rounds 1-5.
//
// Blur design note (r6): lean-body register rolling, ONLY h0/h1 live across
// rows, launch_bounds(512,8) -> 8 waves/SIMD so pure TLP hides the ~900cy row
// load latency. (r7 failed compile: nontemporal builtin rejects HIP_vector_type;
// fixed with native ext_vector_type aliases.)

#define HH 4096
#define WW 4096
#define KRANK 16559111u
#define CAP 65536u

typedef float  nfloat4 __attribute__((ext_vector_type(4)));
typedef int    nint4   __attribute__((ext_vector_type(4)));

__device__ __forceinline__ unsigned ukey(float v) {
  return (unsigned)(v * 268435456.0f);
}
__device__ __forceinline__ int refl(int i) {
  return i < 0 ? -i : (i > 4095 ? 8190 - i : i);
}
__device__ __forceinline__ float grayf(float r, float g, float b) {
  return __fadd_rn(__fadd_rn(__fmul_rn(0.2989f, r), __fmul_rn(0.587f, g)),
                   __fmul_rn(0.114f, b));
}
__device__ __forceinline__ float tap3(float a, float b, float c, float kn0, float kn1) {
  return __fadd_rn(__fadd_rn(__fmul_rn(kn0, a), __fmul_rn(kn1, b)),
                   __fmul_rn(kn0, c));
}

// ---------------- K1: gray + separable blur (lean rolling) + hist1 ---------
// Block = 512 thr = 8 waves = 2 col-spans x 4 row-groups; wave = 256 cols x
// 16 rows (lane = 4 cols). Grid = 8 col-tiles x 64 row-tiles = 512 blocks.
__global__ __launch_bounds__(512, 8) void k_blur(const float* __restrict__ img,
    float* __restrict__ blur, unsigned* __restrict__ hist1,
    float kn0, float kn1) {
  __shared__ unsigned hist[4096];
  const int tid = threadIdx.x;
  for (int i = tid; i < 4096; i += 512) hist[i] = 0u;
  __syncthreads();

  const int lane = tid & 63, wv = tid >> 6;
  const int bc = ((blockIdx.x & 7) << 9) + ((wv & 1) << 8);  // wave col base
  const int rs = ((blockIdx.x >> 3) << 6) + ((wv >> 1) << 4); // wave row base
  const float* __restrict__ Rp = img;
  const float* __restrict__ Gp = img + 16777216;
  const float* __restrict__ Bp = img + 33554432;
  const int c4 = bc + (lane << 2);
  const int colL = (bc == 0) ? 1 : bc - 1;            // reflect(-1)=1
  const int colR = (bc == 3840) ? 4094 : bc + 256;    // reflect(4096)=4094
  const int hc = (lane == 0) ? colL : ((lane == 63) ? colR : c4);

  auto hrow = [&](int r) -> float4 {
    const size_t base = ((size_t)refl(r) << 12);
    float4 R = *(const float4*)(Rp + base + c4);
    float4 G = *(const float4*)(Gp + base + c4);
    float4 B = *(const float4*)(Bp + base + c4);
    float hr = Rp[base + hc], hg = Gp[base + hc], hb = Bp[base + hc];
    float4 g;
    g.x = grayf(R.x, G.x, B.x);
    g.y = grayf(R.y, G.y, B.y);
    g.z = grayf(R.z, G.z, B.z);
    g.w = grayf(R.w, G.w, B.w);
    float ghalo = grayf(hr, hg, hb);
    float gl = __shfl_up(g.w, 1);
    float gr_ = __shfl_down(g.x, 1);
    gl = (lane == 0) ? ghalo : gl;
    gr_ = (lane == 63) ? ghalo : gr_;
    float4 h;
    h.x = tap3(gl, g.x, g.y, kn0, kn1);
    h.y = tap3(g.x, g.y, g.z, kn0, kn1);
    h.z = tap3(g.y, g.z, g.w, kn0, kn1);
    h.w = tap3(g.z, g.w, gr_, kn0, kn1);
    return h;
  };

  float4 h0 = hrow(rs - 1);
  float4 h1 = hrow(rs);
  for (int i = 0; i < 16; ++i) {
    float4 h2 = hrow(rs + 1 + i);
    nfloat4 v;
    v.x = tap3(h0.x, h1.x, h2.x, kn0, kn1);
    v.y = tap3(h0.y, h1.y, h2.y, kn0, kn1);
    v.z = tap3(h0.z, h1.z, h2.z, kn0, kn1);
    v.w = tap3(h0.w, h1.w, h2.w, kn0, kn1);
    __builtin_nontemporal_store(
        v, (nfloat4*)(blur + ((size_t)(rs + i) << 12) + c4));
    atomicAdd(&hist[ukey(v.x) >> 16], 1u);
    atomicAdd(&hist[ukey(v.y) >> 16], 1u);
    atomicAdd(&hist[ukey(v.z) >> 16], 1u);
    atomicAdd(&hist[ukey(v.w) >> 16], 1u);
    h0 = h1; h1 = h2;
  }
  __syncthreads();
  for (int i = tid; i < 4096; i += 512) {
    unsigned c = hist[i];
    if (c) atomicAdd(&hist1[i], c);
  }
}

// ---------------- K2: select level-1 bin containing rank KRANK -------------
__global__ __launch_bounds__(256) void k_sel1(const unsigned* __restrict__ hist1,
                                              unsigned* __restrict__ sel) {
  __shared__ unsigned part[256];
  const int t = threadIdx.x;
  unsigned loc[16];
  unsigned s = 0;
  for (int i = 0; i < 16; ++i) { loc[i] = hist1[t * 16 + i]; s += loc[i]; }
  part[t] = s;
  __syncthreads();
  for (int off = 1; off < 256; off <<= 1) {
    unsigned v = (t >= off) ? part[t - off] : 0u;
    __syncthreads();
    part[t] += v;
    __syncthreads();
  }
  unsigned incl = part[t], excl = incl - s;
  if (excl <= KRANK && KRANK < incl) {
    unsigned p = excl;
    for (int i = 0; i < 16; ++i) {
      if (KRANK < p + loc[i]) { sel[0] = (unsigned)(t * 16 + i); sel[1] = KRANK - p; break; }
      p += loc[i];
    }
  }
}

// ---------------- K3: fused mask bits + hist2 + block-aggregated list ------
// Grid 2048 blocks x 256 thr; block handles 8192 consecutive pixels (2 rows).
__global__ __launch_bounds__(256) void k_pass2(const float* __restrict__ blur,
    const unsigned* __restrict__ sel, unsigned* __restrict__ hist2,
    unsigned* __restrict__ cnt, unsigned long long* __restrict__ list,
    unsigned long long* __restrict__ mbits) {
  __shared__ unsigned lcnt, lbase;
  __shared__ unsigned lidx[256];
  __shared__ unsigned short lkey[256];
  if (threadIdx.x == 0) lcnt = 0u;
  __syncthreads();
  const unsigned b1 = sel[0];
  const unsigned ub = (b1 + 1u) << 16;
  const unsigned base = blockIdx.x * 8192u + threadIdx.x;
  #pragma unroll 4
  for (int it = 0; it < 32; ++it) {
    unsigned i = base + (unsigned)it * 256u;
    unsigned u = ukey(__builtin_nontemporal_load(&blur[i]));
    unsigned long long w = __ballot(u >= ub);
    if ((threadIdx.x & 63) == 0) mbits[i >> 6] = w;
    if ((u >> 16) == b1) {
      atomicAdd(&hist2[u & 0xFFFFu], 1u);
      unsigned x = atomicAdd(&lcnt, 1u);
      if (x < 256u) { lidx[x] = i; lkey[x] = (unsigned short)(u & 0xFFFFu); }
      else {
        unsigned g = atomicAdd(cnt, 1u);
        if (g < CAP) list[g] = ((unsigned long long)i << 16) | (u & 0xFFFFu);
      }
    }
  }
  __syncthreads();
  unsigned n = lcnt > 256u ? 256u : lcnt;
  if (threadIdx.x == 0 && n) lbase = atomicAdd(cnt, n);
  __syncthreads();
  if (threadIdx.x < n) {
    unsigned g = lbase + threadIdx.x;
    if (g < CAP)
      list[g] = ((unsigned long long)lidx[threadIdx.x] << 16) | (unsigned)lkey[threadIdx.x];
  }
}

// ---------------- K4: select low16 of rank key + fixup in-bin mask bits ----
__global__ __launch_bounds__(1024) void k_sel2fix(const unsigned* __restrict__ hist2,
    const unsigned* __restrict__ sel, const unsigned* __restrict__ cnt,
    const unsigned long long* __restrict__ list,
    unsigned long long* __restrict__ mbits) {
  __shared__ unsigned part[1024];
  __shared__ unsigned sLo;
  const int t = threadIdx.x;
  unsigned loc[64];
  const uint4* h4 = (const uint4*)hist2;
  unsigned s = 0;
  #pragma unroll
  for (int j = 0; j < 16; ++j) {
    uint4 q = h4[t * 16 + j];
    loc[4 * j] = q.x; loc[4 * j + 1] = q.y; loc[4 * j + 2] = q.z; loc[4 * j + 3] = q.w;
    s += q.x + q.y + q.z + q.w;
  }
  part[t] = s;
  __syncthreads();
  for (int off = 1; off < 1024; off <<= 1) {
    unsigned v = (t >= off) ? part[t - off] : 0u;
    __syncthreads();
    part[t] += v;
    __syncthreads();
  }
  unsigned incl = part[t], excl = incl - s;
  const unsigned r1 = sel[1];
  if (excl <= r1 && r1 < incl) {
    unsigned p = excl;
    for (int i = 0; i < 64; ++i) {
      if (r1 < p + loc[i]) { sLo = (unsigned)t * 64u + i; break; }
      p += loc[i];
    }
  }
  __syncthreads();
  const unsigned lo = sLo;
  unsigned n = *cnt; if (n > CAP) n = CAP;
  for (unsigned j = t; j < n; j += 1024) {
    unsigned long long e = list[j];
    if ((unsigned)(e & 0xFFFFu) >= lo) {
      unsigned long long pix = e >> 16;
      atomicOr(&mbits[pix >> 6], 1ull << (pix & 63));
    }
  }
}

// ---------------- K5: fused 5x5 erode (zero border) + dilate + int32 out ---
__global__ __launch_bounds__(256) void k_morph(
    const unsigned long long* __restrict__ mbits, int* __restrict__ out) {
  __shared__ unsigned long long er[12][64];
  __shared__ unsigned long long dl[8][64];
  const int r0 = blockIdx.x << 3;
  for (int t = threadIdx.x; t < 12 * 64; t += 256) {
    int lr = t >> 6, wc = t & 63;
    int rr = r0 - 2 + lr;
    unsigned long long acc = 0ull;
    if (rr >= 0 && rr < HH) {
      acc = ~0ull;
      #pragma unroll
      for (int dr = -2; dr <= 2; ++dr) {
        int mr = rr + dr;
        unsigned long long h = 0ull;
        if (mr >= 0 && mr < HH) {
          int rb = (mr << 6) + wc;
          unsigned long long C = mbits[rb];
          unsigned long long L = (wc > 0) ? mbits[rb - 1] : 0ull;
          unsigned long long R = (wc < 63) ? mbits[rb + 1] : 0ull;
          h = C & ((C >> 1) | (R << 63)) & ((C >> 2) | (R << 62))
                & ((C << 1) | (L >> 63)) & ((C << 2) | (L >> 62));
        }
        acc &= h;
      }
    }
    er[lr][wc] = acc;
  }
  __syncthreads();
  for (int t = threadIdx.x; t < 8 * 64; t += 256) {
    int lr = t >> 6, wc = t & 63;
    unsigned long long acc = 0ull;
    #pragma unroll
    for (int dr = 0; dr <= 4; ++dr) {
      unsigned long long C = er[lr + dr][wc];
      unsigned long long L = (wc > 0) ? er[lr + dr][wc - 1] : 0ull;
      unsigned long long R = (wc < 63) ? er[lr + dr][wc + 1] : 0ull;
      acc |= C | ((C >> 1) | (R << 63)) | ((C >> 2) | (R << 62))
               | ((C << 1) | (L >> 63)) | ((C << 2) | (L >> 62));
    }
    dl[lr][wc] = acc;
  }
  __syncthreads();
  const size_t p0 = (size_t)r0 << 12;       // out element base (4096/row)
  for (int j = threadIdx.x; j < 8192; j += 256) {
    unsigned long long word = dl[j >> 10][(j >> 4) & 63];
    unsigned nib = (unsigned)(word >> ((j & 15) << 2)) & 0xFu;
    nint4 o;
    o.x = (int)(nib & 1); o.y = (int)((nib >> 1) & 1);
    o.z = (int)((nib >> 2) & 1); o.w = (int)((nib >> 3) & 1);
    __builtin_nontemporal_store(o, (nint4*)(out + p0 + (size_t)j * 4));
  }
}

// ---------------------------------------------------------------------------
extern "C" void kernel_launch(void* const* d_in, const int* in_sizes, int n_in,
                              void* d_out, int out_size, void* d_ws, size_t ws_size,
                              hipStream_t stream) {
  (void)in_sizes; (void)n_in; (void)out_size; (void)ws_size;
  const float* img = (const float*)d_in[0];
  char* ws = (char*)d_ws;

  float* blur = (float*)ws;                                          // 64 MB
  unsigned long long* mbits = (unsigned long long*)(ws + 67108864);  // 2 MB
  unsigned* hist1 = (unsigned*)(ws + 69206016);                      // 16 KB
  unsigned* hist2 = (unsigned*)(ws + 69222400);                      // 256 KB
  unsigned* cnt   = (unsigned*)(ws + 69484544);                      // 64 B
  unsigned* sel   = (unsigned*)(ws + 69484608);                      // 64 B
  unsigned long long* list = (unsigned long long*)(ws + 69484672);   // 512 KB

  float t = 1.0f / 0.8f;
  float k0 = expf(-0.5f * (t * t));
  float k1 = 1.0f;
  float s = (k0 + k1) + k0;
  float kn0 = k0 / s, kn1 = k1 / s;

  (void)hipMemsetAsync(hist1, 0, 16384 + 262144 + 64, stream);  // hist1+hist2+cnt
  k_blur<<<512, 512, 0, stream>>>(img, blur, hist1, kn0, kn1);
  k_sel1<<<1, 256, 0, stream>>>(hist1, sel);
  k_pass2<<<2048, 256, 0, stream>>>(blur, sel, hist2, cnt, list, mbits);
  k_sel2fix<<<1, 1024, 0, stream>>>(hist2, sel, cnt, list, mbits);
  k_morph<<<512, 256, 0, stream>>>(mbits, (int*)d_out);
}